// Round 12
// baseline (343.236 us; speedup 1.0000x reference)
//
#include <hip/hip_runtime.h>
#include <math.h>

#define NB 64
#define NN 197
#define NC 768
#define NH 12
#define ND 64
#define KCB 50
#define NM (NN-1)                    // 196
#define BNROWS (NB*NN)               // 12608
#define SZ ((size_t)NB*NH*NN*ND)     // 9,682,944
#define WQKV ((size_t)2304*768)      // 1,769,472
#define WPRJ ((size_t)768*768)       // 589,824

typedef unsigned short u16;
typedef unsigned int u32;
typedef unsigned long long u64;
typedef _Float16 h2 __attribute__((ext_vector_type(2)));
typedef _Float16 f16x4 __attribute__((ext_vector_type(4)));
typedef _Float16 f16x8 __attribute__((ext_vector_type(8)));
typedef float f32x4 __attribute__((ext_vector_type(4)));

#define GLOAD16(gp, lp) __builtin_amdgcn_global_load_lds( \
    (const __attribute__((address_space(1))) void*)(gp),  \
    (__attribute__((address_space(3))) void*)(lp), 16, 0, 0)

__device__ __forceinline__ u16 f2h(float x) {
  _Float16 h = (_Float16)x;
  return *(u16*)&h;
}
__device__ __forceinline__ float h2f(u16 b) { _Float16 h = *(_Float16*)&b; return (float)h; }

// ---------------- split fp32 -> f16 hi (+ optional lo) planes ----------------
template<bool LO>
__global__ __launch_bounds__(256)
void split_kernel(const float* __restrict__ src, u16* __restrict__ hi,
                  u16* __restrict__ lo, int n4)
{
  int i = blockIdx.x*256 + threadIdx.x;
  if (i >= n4) return;
  float4 v = ((const float4*)src)[i];
  _Float16 h0 = (_Float16)v.x, h1 = (_Float16)v.y, h2_ = (_Float16)v.z, h3 = (_Float16)v.w;
  uint2 hv = make_uint2((u32)*(u16*)&h0 | ((u32)*(u16*)&h1 << 16),
                        (u32)*(u16*)&h2_ | ((u32)*(u16*)&h3 << 16));
  ((uint2*)hi)[i] = hv;
  if constexpr (LO) {
    _Float16 l0 = (_Float16)(v.x - (float)h0), l1 = (_Float16)(v.y - (float)h1);
    _Float16 l2 = (_Float16)(v.z - (float)h2_), l3 = (_Float16)(v.w - (float)h3);
    uint2 lv = make_uint2((u32)*(u16*)&l0 | ((u32)*(u16*)&l1 << 16),
                          (u32)*(u16*)&l2 | ((u32)*(u16*)&l3 << 16));
    ((uint2*)lo)[i] = lv;
  }
}

// ---------------- MFMA GEMM, f16 split, C[r,o] = sum_c A[r,c]*W[o,c] ----------------
// 1D grid, XCD-chunked bijective remap, col-fastest within chunk.
// Counted-vmcnt pipeline (depth 2) with RAW s_barrier (no vmcnt(0) drain per iter):
//   prologue: stage(0), stage(1)
//   iter kt:  vmcnt(LPS) [stage(kt) landed, stage(kt+1) in flight] -> barrier ->
//             setprio(1) MFMA setprio(0) -> barrier -> stage(kt+2 into buf cur)
// MODE 0: qkv, A = xh/xl planes; q/k cols split-3, v cols hi*hi; q/k out as hi/lo planes.
// MODE 1: proj, A = aoh f16, hi-only + bias.
template<int MODE>
__global__ __launch_bounds__(256)
void gemm_mfma(const u16* __restrict__ Ah, const u16* __restrict__ Al,
               const u16* __restrict__ Wh, const u16* __restrict__ Wl,
               u16* __restrict__ qh_, u16* __restrict__ ql_,
               u16* __restrict__ kh_, u16* __restrict__ kl_, u16* __restrict__ vb_,
               const float* __restrict__ bias, float* __restrict__ dout)
{
  constexpr int NPL = (MODE == 1) ? 2 : 4;
  constexpr int NBX = (MODE == 1) ? 6 : 18;     // col blocks
  constexpr int NWG = NBX * 99;
  constexpr int Q8 = NWG / 8, R8 = NWG % 8;
  __shared__ u16 lds[2][NPL][4096];   // [buf][plane][128 rows x 32 f16]
  const int tid = threadIdx.x;
  const int lane = tid & 63, w = tid >> 6;
  const int wm = w >> 1, wn = w & 1;
  const int wg = blockIdx.x;
  const int xcd = wg & 7, cidx = wg >> 3;
  const int work = (xcd < R8 ? xcd*(Q8+1) : R8*(Q8+1) + (xcd-R8)*Q8) + cidx;
  const int row0 = (work / NBX) * 128, col0 = (work % NBX) * 128;
  const bool dolo = (MODE == 0) && (col0 < 1536);   // q/k need split-3; v hi-only

  f32x4 acc[4][4];
  #pragma unroll
  for (int mi = 0; mi < 4; ++mi)
    #pragma unroll
    for (int ni = 0; ni < 4; ++ni) acc[mi][ni] = (f32x4){0.f, 0.f, 0.f, 0.f};

  auto stage = [&](int buf, int kt) {
    const int c0 = kt * 32;
    #pragma unroll
    for (int j = 0; j < 2; ++j) {
      const int r0 = w*32 + j*16;
      const int lrow = r0 + (lane >> 2);
      const int slot = (lane & 3) ^ (lrow & 3);
      int ar = row0 + lrow; if (ar > BNROWS-1) ar = BNROWS-1;
      const size_t ga = (size_t)ar * 768 + c0 + slot*8;
      const size_t gb = (size_t)(col0 + lrow) * 768 + c0 + slot*8;
      GLOAD16(Ah + ga, &lds[buf][0][r0*32]);
      GLOAD16(Wh + gb, &lds[buf][1][r0*32]);
      if constexpr (MODE == 0) {
        if (dolo) {
          GLOAD16(Al + ga, &lds[buf][2][r0*32]);
          GLOAD16(Wl + gb, &lds[buf][3][r0*32]);
        }
      }
    }
  };

  auto compute = [&](int buf) {
    f16x8 ah[4], bh[4];
    const int g = lane >> 4;
    int offa[4], offb[4];
    #pragma unroll
    for (int mi = 0; mi < 4; ++mi) {
      int arow = wm*64 + mi*16 + (lane & 15);
      offa[mi] = arow*32 + ((g ^ (arow & 3)) << 3);
      ah[mi] = *(const f16x8*)&lds[buf][0][offa[mi]];
    }
    #pragma unroll
    for (int ni = 0; ni < 4; ++ni) {
      int brow = wn*64 + ni*16 + (lane & 15);
      offb[ni] = brow*32 + ((g ^ (brow & 3)) << 3);
      bh[ni] = *(const f16x8*)&lds[buf][1][offb[ni]];
    }
    #pragma unroll
    for (int mi = 0; mi < 4; ++mi)
      #pragma unroll
      for (int ni = 0; ni < 4; ++ni)
        acc[mi][ni] = __builtin_amdgcn_mfma_f32_16x16x32_f16(ah[mi], bh[ni], acc[mi][ni], 0, 0, 0);
    if constexpr (MODE == 0) {
      if (dolo) {
        f16x8 al[4], bl[4];
        #pragma unroll
        for (int mi = 0; mi < 4; ++mi) al[mi] = *(const f16x8*)&lds[buf][2][offa[mi]];
        #pragma unroll
        for (int ni = 0; ni < 4; ++ni) bl[ni] = *(const f16x8*)&lds[buf][3][offb[ni]];
        #pragma unroll
        for (int mi = 0; mi < 4; ++mi)
          #pragma unroll
          for (int ni = 0; ni < 4; ++ni) {
            acc[mi][ni] = __builtin_amdgcn_mfma_f32_16x16x32_f16(ah[mi], bl[ni], acc[mi][ni], 0, 0, 0);
            acc[mi][ni] = __builtin_amdgcn_mfma_f32_16x16x32_f16(al[mi], bh[ni], acc[mi][ni], 0, 0, 0);
          }
      }
    }
  };

  // prologue: two tiles in flight
  stage(0, 0);
  stage(1, 1);
  int cur = 0;
  for (int kt = 0; kt < 24; ++kt) {
    if (kt < 23) {
      if (MODE == 0 && dolo) asm volatile("s_waitcnt vmcnt(8)" ::: "memory");
      else                   asm volatile("s_waitcnt vmcnt(4)" ::: "memory");
    } else {
      asm volatile("s_waitcnt vmcnt(0)" ::: "memory");
    }
    __builtin_amdgcn_s_barrier();
    __builtin_amdgcn_sched_barrier(0);
    __builtin_amdgcn_s_setprio(1);
    compute(cur);
    __builtin_amdgcn_s_setprio(0);
    __builtin_amdgcn_sched_barrier(0);
    __builtin_amdgcn_s_barrier();
    __builtin_amdgcn_sched_barrier(0);
    if (kt + 2 < 24) stage(cur, kt + 2);
    cur ^= 1;
  }

  float* biasl = nullptr;
  if constexpr (MODE == 1) {
    biasl = (float*)&lds[0][0][0];
    if (tid < 128) biasl[tid] = bias[col0 + tid];
    __syncthreads();
  }
  #pragma unroll
  for (int mi = 0; mi < 4; ++mi) {
    #pragma unroll
    for (int t = 0; t < 4; ++t) {
      int r = row0 + wm*64 + mi*16 + (lane >> 4)*4 + t;
      if (r >= BNROWS) continue;
      if constexpr (MODE == 0) {
        int b_ = r / 197, n_ = r - b_*197;
        #pragma unroll
        for (int ni = 0; ni < 4; ++ni) {
          int o = col0 + wn*64 + ni*16 + (lane & 15);
          float val = acc[mi][ni][t];
          int tq = o / 768, rem = o - tq*768;
          int hh = rem >> 6, dd = rem & 63;
          size_t dst = ((size_t)(b_*12 + hh)*197 + n_)*64 + dd;
          u16 hi = f2h(val);
          if (tq == 0)      { qh_[dst] = hi; ql_[dst] = f2h(val - h2f(hi)); }
          else if (tq == 1) { kh_[dst] = hi; kl_[dst] = f2h(val - h2f(hi)); }
          else              vb_[dst] = hi;
        }
      } else {
        #pragma unroll
        for (int ni = 0; ni < 4; ++ni) {
          int o = col0 + wn*64 + ni*16 + (lane & 15);
          dout[(size_t)r*768 + o] = acc[mi][ni][t] + biasl[o - col0];
        }
      }
    }
  }
}

// ---------------- Quantize via MFMA distance GEMM + fp64 rescue for near-ties ----------
__global__ __launch_bounds__(256)
void quant_mfma(const float* __restrict__ x, const float* __restrict__ qkv_w,
                const u16* __restrict__ qh, const u16* __restrict__ ql,
                const u16* __restrict__ kh, const u16* __restrict__ kl,
                const float* __restrict__ qe, const float* __restrict__ ke,
                u16* __restrict__ cq, u16* __restrict__ ck, float* __restrict__ pq)
{
  __shared__ __align__(16) float El[KCB*66];    // codebook fp32 (pad 66)
  __shared__ __align__(16) u16 Ehi[64*64];      // codebook f16 hi (rows 50..63 zero)
  __shared__ __align__(16) u16 Elo[64*64];      // codebook f16 lo
  __shared__ double e2d[KCB];
  __shared__ int idxb[NM];
  __shared__ float wred[4];
  const int tid = threadIdx.x;
  const int bh = blockIdx.x;
  const int which = blockIdx.y;
  const int b_ = bh / 12, h_ = bh - b_*12;
  const u16* feath = which ? kh : qh;
  const u16* featl = which ? kl : ql;
  const float* emb  = which ? ke : qe;
  u16* dst = which ? ck : cq;
  const size_t base = (size_t)bh * (197*64);
  const int lane = tid & 63, w = tid >> 6;
  const int ln = lane & 15, g = lane >> 4;

  for (int idx = tid; idx < KCB*64; idx += 256) {
    int kk = idx >> 6, i = idx & 63;
    float v = emb[h_*(KCB*64) + idx];
    El[kk*66 + i] = v;
    _Float16 hv = (_Float16)v;
    Ehi[idx] = *(u16*)&hv;
    _Float16 lv = (_Float16)(v - (float)hv);
    Elo[idx] = *(u16*)&lv;
  }
  for (int idx = tid; idx < 14*64; idx += 256) {
    Ehi[KCB*64 + idx] = 0; Elo[KCB*64 + idx] = 0;
  }
  if (tid >= 64 && tid < 128) {
    int i = tid - 64;
    dst[base + i] = feath[base + i];      // cls passthrough
  }
  __syncthreads();
  if (tid < KCB) {
    double s = 0.0;
    for (int i = 0; i < 64; ++i) { double e = (double)El[tid*66 + i]; s += e*e; }
    e2d[tid] = s;
  }
  __syncthreads();

  f16x8 Eah[4][2], Eal[4][2];
  float e2l[4][4];
  #pragma unroll
  for (int t = 0; t < 4; ++t) {
    #pragma unroll
    for (int s = 0; s < 2; ++s) {
      int off = (t*16 + ln)*64 + s*32 + g*8;
      Eah[t][s] = *(const f16x8*)&Ehi[off];
      Eal[t][s] = *(const f16x8*)&Elo[off];
    }
    #pragma unroll
    for (int r = 0; r < 4; ++r) {
      int c = t*16 + g*4 + r;
      e2l[t][r] = (c < KCB) ? (float)e2d[c] : 1e30f;
    }
  }

  float msum = 0.f;
  for (int nt = w; nt < 13; nt += 4) {
    int tok = nt*16 + ln;
    int tokc = tok < NM ? tok : NM-1;
    const u16* fh = feath + base + (size_t)(tokc+1)*64;
    const u16* fl = featl + base + (size_t)(tokc+1)*64;
    f16x8 fqh[2], fql[2];
    float f2 = 0.f;
    #pragma unroll
    for (int s = 0; s < 2; ++s) {
      uint4 uh = *(const uint4*)(fh + s*32 + g*8);
      uint4 ul = *(const uint4*)(fl + s*32 + g*8);
      fqh[s] = *(f16x8*)&uh;
      fql[s] = *(f16x8*)&ul;
      #pragma unroll
      for (int i = 0; i < 8; ++i) {
        float q = (float)fqh[s][i] + (float)fql[s][i];
        f2 = fmaf(q, q, f2);
      }
    }
    f32x4 dacc[4];
    #pragma unroll
    for (int t = 0; t < 4; ++t) dacc[t] = (f32x4){0.f,0.f,0.f,0.f};
    #pragma unroll
    for (int t = 0; t < 4; ++t)
      #pragma unroll
      for (int s = 0; s < 2; ++s) {
        dacc[t] = __builtin_amdgcn_mfma_f32_16x16x32_f16(Eah[t][s], fqh[s], dacc[t], 0, 0, 0);
        dacc[t] = __builtin_amdgcn_mfma_f32_16x16x32_f16(Eah[t][s], fql[s], dacc[t], 0, 0, 0);
        dacc[t] = __builtin_amdgcn_mfma_f32_16x16x32_f16(Eal[t][s], fqh[s], dacc[t], 0, 0, 0);
      }
    float d1 = 1e38f, d2 = 1e38f; int idx = 0;
    #pragma unroll
    for (int t = 0; t < 4; ++t)
      #pragma unroll
      for (int r = 0; r < 4; ++r) {
        int c = t*16 + g*4 + r;
        float d = fmaf(-2.f, dacc[t][r], e2l[t][r]);
        if (d < d1) { d2 = d1; d1 = d; idx = c; }
        else if (d < d2) d2 = d;
      }
    #pragma unroll
    for (int off = 16; off <= 32; off <<= 1) {
      float od1 = __shfl_xor(d1, off), od2 = __shfl_xor(d2, off);
      int   oi  = __shfl_xor(idx, off);
      float of2 = __shfl_xor(f2, off);
      f2 += of2;
      if (od1 < d1 || (od1 == d1 && oi < idx)) {
        d2 = fminf(d1, od2); d1 = od1; idx = oi;
      } else {
        d2 = fminf(d2, od1);
      }
    }
    bool valid = tok < NM;
    bool exact = false;
    u64 flags = __ballot(g == 0 && valid && (d2 - d1) < 1e-3f);
    while (flags) {
      int src = __ffsll(flags) - 1;
      flags &= flags - 1;
      int mrow = 1 + nt*16 + src;
      const float* xrow = x + (size_t)(b_*197 + mrow)*768;
      const float* wrow = qkv_w + (size_t)(which*768 + h_*64 + lane)*768;
      double qd0 = 0.0, qd1 = 0.0, qd2 = 0.0, qd3 = 0.0;
      for (int c = 0; c < 768; c += 4) {
        qd0 = fma((double)xrow[c],   (double)wrow[c],   qd0);
        qd1 = fma((double)xrow[c+1], (double)wrow[c+1], qd1);
        qd2 = fma((double)xrow[c+2], (double)wrow[c+2], qd2);
        qd3 = fma((double)xrow[c+3], (double)wrow[c+3], qd3);
      }
      double qd = (qd0 + qd1) + (qd2 + qd3);
      double bb = 1e300; int bi = 0;
      for (int kk = 0; kk < KCB; ++kk) {
        double df = qd - (double)El[kk*66 + lane];
        double sq = df*df;
        #pragma unroll
        for (int off = 32; off > 0; off >>= 1) sq += __shfl_xor(sq, off);
        if (sq < bb) { bb = sq; bi = kk; }
      }
      if (ln == src) { idx = bi; d1 = (float)bb; exact = true; }
    }
    if (g == 0 && valid) {
      idxb[tok] = idx;
      msum += exact ? d1 : (d1 + f2);
    }
  }
  __syncthreads();

  for (int idx = tid; idx < NM*64; idx += 256) {
    int mm = idx >> 6, i = idx & 63;
    dst[base + (size_t)(mm+1)*64 + i] = f2h(El[idxb[mm]*66 + i]);
  }

  #pragma unroll
  for (int off = 8; off > 0; off >>= 1) msum += __shfl_down(msum, off);
  if (lane == 0) wred[w] = msum;
  __syncthreads();
  if (tid == 0) pq[which*768 + bh] = wred[0]+wred[1]+wred[2]+wred[3];
}

// ---------------- fused attention via MFMA, SINGLE-PASS online softmax ----------
__global__ __launch_bounds__(256)
void fused_attn_mfma(const u16* __restrict__ qh, const u16* __restrict__ kh,
                     const u16* __restrict__ cq, const u16* __restrict__ ck,
                     const u16* __restrict__ vb,
                     u16* __restrict__ aoh, float* __restrict__ pkl)
{
  __shared__ __align__(16) u16 Kf[200*64];    // XOR-swizzled rows (slot^=row&7)
  __shared__ __align__(16) u16 CKf[200*64];
  __shared__ __align__(16) u16 Vt[64*212];    // V transposed [d][m], stride 212
  __shared__ float wred[4];
  const int tid = threadIdx.x;
  const int bh = blockIdx.x;
  const int b_ = bh / 12, h_ = bh - b_*12;
  const size_t base = (size_t)bh * (197*64);
  const u32* kh32 = (const u32*)kh;
  const u32* ck32 = (const u32*)ck;
  const u32* vb32 = (const u32*)vb;
  const size_t base2 = base >> 1;

  for (int idx = tid; idx < 197*32; idx += 256) {
    int m = idx >> 5, j = idx & 31;
    int dsti = m*32 + (((j >> 2) ^ (m & 7)) << 2) + (j & 3);
    ((u32*)Kf)[dsti] = kh32[base2 + idx];
    ((u32*)CKf)[dsti] = ck32[base2 + idx];
    u32 v2 = vb32[base2 + idx];
    Vt[(2*j)*212 + m]   = (u16)(v2 & 0xffff);
    Vt[(2*j+1)*212 + m] = (u16)(v2 >> 16);
  }
  for (int idx = tid; idx < 96; idx += 256) {
    int m = 197 + (idx >> 5), j = idx & 31;
    int dsti = m*32 + (((j >> 2) ^ (m & 7)) << 2) + (j & 3);
    ((u32*)Kf)[dsti] = 0; ((u32*)CKf)[dsti] = 0;
  }
  for (int idx = tid; idx < 64*15; idx += 256) {
    int d = idx / 15, mc = 197 + idx % 15;
    Vt[d*212 + mc] = 0;
  }
  __syncthreads();

  const int lane = tid & 63, w = tid >> 6;
  const int ln = lane & 15, g = lane >> 4;
  float klacc = 0.f;

  for (int nt = w; nt < 13; nt += 4) {
    const int n0 = nt*16;
    const int nb = n0 + ln;
    f16x8 fq[2], fcq[2];
    #pragma unroll
    for (int s = 0; s < 2; ++s) {
      uint4 qu = *(const uint4*)(qh + base + (size_t)nb*64 + s*32 + g*8);
      fq[s] = *(f16x8*)&qu;
      uint4 cu = *(const uint4*)(cq + base + (size_t)nb*64 + s*32 + g*8);
      fcq[s] = *(f16x8*)&cu;
    }

    float Ma = -3e38f, Mq = -3e38f;
    float aS = 0.f, aT = 0.f, qS = 0.f, cross = 0.f;
    f32x4 ov[4];
    #pragma unroll
    for (int dt = 0; dt < 4; ++dt) ov[dt] = (f32x4){0.f,0.f,0.f,0.f};

    for (int t = 0; t < 13; ++t) {
      int mrow = t*16 + ln; if (mrow > 199) mrow = 199;
      const char* kb8 = (const char*)Kf + mrow*128;
      const char* cb8 = (const char*)CKf + mrow*128;
      int sw = (mrow & 7) << 4;
      f32x4 sa = (f32x4){0.f,0.f,0.f,0.f}, sq = (f32x4){0.f,0.f,0.f,0.f};
      sa = __builtin_amdgcn_mfma_f32_16x16x32_f16(*(const f16x8*)(kb8 + (( g     <<4) ^ sw)), fq[0], sa, 0,0,0);
      sa = __builtin_amdgcn_mfma_f32_16x16x32_f16(*(const f16x8*)(kb8 + (((4+g)<<4) ^ sw)), fq[1], sa, 0,0,0);
      sq = __builtin_amdgcn_mfma_f32_16x16x32_f16(*(const f16x8*)(cb8 + (( g     <<4) ^ sw)), fcq[0], sq, 0,0,0);
      sq = __builtin_amdgcn_mfma_f32_16x16x32_f16(*(const f16x8*)(cb8 + (((4+g)<<4) ^ sw)), fcq[1], sq, 0,0,0);
      int mbase = t*16 + g*4;
      float tma = -3e38f, tmq = -3e38f;
      #pragma unroll
      for (int r = 0; r < 4; ++r) {
        bool v = (mbase + r) < 197;
        tma = fmaxf(tma, v ? sa[r] : -3e38f);
        tmq = fmaxf(tmq, v ? sq[r] : -3e38f);
      }
      tma = fmaxf(tma, __shfl_xor(tma, 16)); tma = fmaxf(tma, __shfl_xor(tma, 32));
      tmq = fmaxf(tmq, __shfl_xor(tmq, 16)); tmq = fmaxf(tmq, __shfl_xor(tmq, 32));
      float Ma2 = fmaxf(Ma, tma), Mq2 = fmaxf(Mq, tmq);
      float sca = __expf(0.125f*(Ma - Ma2));
      float scq = __expf(0.125f*(Mq - Mq2));
      Ma = Ma2; Mq = Mq2;
      aS *= sca; aT *= sca; qS *= scq; cross *= sca*scq;
      float s0 = __shfl(scq, g*4+0), s1 = __shfl(scq, g*4+1);
      float s2 = __shfl(scq, g*4+2), s3 = __shfl(scq, g*4+3);
      #pragma unroll
      for (int dt = 0; dt < 4; ++dt) {
        ov[dt][0] *= s0; ov[dt][1] *= s1; ov[dt][2] *= s2; ov[dt][3] *= s3;
      }
      const float mla = 0.125f*Ma, mlq = 0.125f*Mq;
      float eqv[4];
      #pragma unroll
      for (int r = 0; r < 4; ++r) {
        bool v = (mbase + r) < 197;
        float ea = v ? __expf(fmaf(sa[r], 0.125f, -mla)) : 0.f;
        float eq = v ? __expf(fmaf(sq[r], 0.125f, -mlq)) : 0.f;
        aS += ea;
        aT = fmaf(ea, sa[r], aT);
        qS += eq;
        cross = fmaf(ea, eq, cross);
        eqv[r] = eq;
      }
      f16x4 qaf = {(_Float16)eqv[0], (_Float16)eqv[1], (_Float16)eqv[2], (_Float16)eqv[3]};
      #pragma unroll
      for (int dt = 0; dt < 4; ++dt) {
        f16x4 bv = *(const f16x4*)(Vt + (dt*16 + ln)*212 + t*16 + g*4);
        ov[dt] = __builtin_amdgcn_mfma_f32_16x16x16f16(qaf, bv, ov[dt], 0, 0, 0);
      }
    }
    aS += __shfl_xor(aS, 16); aS += __shfl_xor(aS, 32);
    aT += __shfl_xor(aT, 16); aT += __shfl_xor(aT, 32);
    qS += __shfl_xor(qS, 16); qS += __shfl_xor(qS, 32);
    cross += __shfl_xor(cross, 16); cross += __shfl_xor(cross, 32);

    if (g == 0 && nb < 197) {
      float rowkl = 0.125f*(aT/aS) - 0.125f*Ma - __logf(aS) - cross/(aS*qS);
      klacc += rowkl;
    }
    #pragma unroll
    for (int r = 0; r < 4; ++r) {
      int nl = g*4 + r;
      int nglob = n0 + nl;
      if (nglob >= 197) continue;
      float qSn = __shfl(qS, nl);
      float inv = __frcp_rn(qSn);
      size_t obase = ((size_t)(b_*197 + nglob))*768 + h_*64;
      #pragma unroll
      for (int dt = 0; dt < 4; ++dt)
        aoh[obase + dt*16 + ln] = f2h(ov[dt][r] * inv);
    }
  }

  #pragma unroll
  for (int off = 32; off > 0; off >>= 1) klacc += __shfl_down(klacc, off);
  if (lane == 0) wred[w] = klacc;
  __syncthreads();
  if (tid == 0) pkl[bh] = wred[0] + wred[1] + wred[2] + wred[3];
}

// ---------------- deterministic loss finalize ----------------
__global__ __launch_bounds__(256)
void finalize_kernel(const float* __restrict__ pq, const float* __restrict__ pkl,
                     float* __restrict__ dout)
{
  __shared__ double red[256];
  const int tid = threadIdx.x;
  double s0 = 0.0, s1 = 0.0;
  for (int i = tid; i < 1536; i += 256) s0 += (double)pq[i];
  for (int i = tid; i < 768; i += 256) s1 += (double)pkl[i];
  red[tid] = s0; __syncthreads();
  for (int off = 128; off > 0; off >>= 1) { if (tid < off) red[tid] += red[tid+off]; __syncthreads(); }
  double mse = red[0];
  __syncthreads();
  red[tid] = s1; __syncthreads();
  for (int off = 128; off > 0; off >>= 1) { if (tid < off) red[tid] += red[tid+off]; __syncthreads(); }
  double kl = red[0];
  if (tid == 0) dout[SZ] = (float)(mse / 9633792.0 + kl / 29805312.0);
}

extern "C" void kernel_launch(void* const* d_in, const int* in_sizes, int n_in,
                              void* d_out, int out_size, void* d_ws, size_t ws_size,
                              hipStream_t stream)
{
  const float* x      = (const float*)d_in[0];
  const float* qkv_w  = (const float*)d_in[1];
  const float* proj_w = (const float*)d_in[2];
  const float* proj_b = (const float*)d_in[3];
  const float* qe     = (const float*)d_in[4];
  const float* ke     = (const float*)d_in[5];
  float* out = (float*)d_out;

  u16* ws16 = (u16*)d_ws;
  u16* qh_ = ws16;                       // SZ f16 planes
  u16* ql_ = qh_ + SZ;
  u16* kh_ = ql_ + SZ;
  u16* kl_ = kh_ + SZ;
  u16* vb_ = kl_ + SZ;
  u16* cq_ = vb_ + SZ;
  u16* ck_ = cq_ + SZ;
  u16* aoh_= ck_ + SZ;
  u16* xh_ = aoh_ + SZ;
  u16* xl_ = xh_ + SZ;
  u16* wh_ = xl_ + SZ;                   // WQKV f16
  u16* wl_ = wh_ + WQKV;
  u16* ph_ = wl_ + WQKV;                 // WPRJ f16
  float* pq_ = (float*)(ph_ + WPRJ);     // 1536
  float* pkl_= pq_ + 1536;               // 768

  dim3 blk(256);
  split_kernel<true><<<dim3((int)(SZ/4/256)),   blk, 0, stream>>>(x, xh_, xl_, (int)(SZ/4));
  split_kernel<true><<<dim3((int)(WQKV/4/256)), blk, 0, stream>>>(qkv_w, wh_, wl_, (int)(WQKV/4));
  split_kernel<false><<<dim3((int)(WPRJ/4/256)), blk, 0, stream>>>(proj_w, ph_, nullptr, (int)(WPRJ/4));
  gemm_mfma<0><<<dim3(99*18), blk, 0, stream>>>(xh_, xl_, wh_, wl_, qh_, ql_, kh_, kl_, vb_, nullptr, nullptr);
  quant_mfma<<<dim3(768, 2), blk, 0, stream>>>(x, qkv_w, qh_, ql_, kh_, kl_, qe, ke, cq_, ck_, pq_);
  fused_attn_mfma<<<dim3(768), blk, 0, stream>>>(qh_, kh_, cq_, ck_, vb_, aoh_, pkl_);
  gemm_mfma<1><<<dim3(99*6), blk, 0, stream>>>(aoh_, nullptr, ph_, nullptr, nullptr, nullptr, nullptr, nullptr, nullptr, proj_b, out);
  finalize_kernel<<<dim3(1), blk, 0, stream>>>(pq_, pkl_, out);
}

// Round 13
// 335.355 us; speedup vs baseline: 1.0235x; 1.0235x over previous
//
#include <hip/hip_runtime.h>
#include <math.h>

#define NB 64
#define NN 197
#define NC 768
#define NH 12
#define ND 64
#define KCB 50
#define NM (NN-1)                    // 196
#define BNROWS (NB*NN)               // 12608
#define SZ ((size_t)NB*NH*NN*ND)     // 9,682,944
#define WQKV ((size_t)2304*768)      // 1,769,472
#define WPRJ ((size_t)768*768)       // 589,824

typedef unsigned short u16;
typedef unsigned int u32;
typedef unsigned long long u64;
typedef _Float16 h2 __attribute__((ext_vector_type(2)));
typedef _Float16 f16x4 __attribute__((ext_vector_type(4)));
typedef _Float16 f16x8 __attribute__((ext_vector_type(8)));
typedef float f32x4 __attribute__((ext_vector_type(4)));

#define GLOAD16(gp, lp) __builtin_amdgcn_global_load_lds( \
    (const __attribute__((address_space(1))) void*)(gp),  \
    (__attribute__((address_space(3))) void*)(lp), 16, 0, 0)

__device__ __forceinline__ u16 f2h(float x) {
  _Float16 h = (_Float16)x;
  return *(u16*)&h;
}
__device__ __forceinline__ float h2f(u16 b) { _Float16 h = *(_Float16*)&b; return (float)h; }

// ---------------- fused split: x (hi+lo), qkv_w (hi+lo), proj_w (hi) in ONE launch ----------
#define XQ4 ((int)(SZ/4))      // 2,420,736 quads
#define WQ4 ((int)(WQKV/4))    //   442,368
#define PQ4 ((int)(WPRJ/4))    //   147,456
#define TOTQ4 (XQ4 + WQ4 + PQ4)

__global__ __launch_bounds__(256)
void split_all(const float* __restrict__ x, const float* __restrict__ qkv_w,
               const float* __restrict__ proj_w,
               u16* __restrict__ xh, u16* __restrict__ xl,
               u16* __restrict__ wh, u16* __restrict__ wl,
               u16* __restrict__ ph)
{
  for (int i = blockIdx.x*256 + threadIdx.x; i < TOTQ4; i += gridDim.x*256) {
    const float* src; u16* hi; u16* lo; int j;
    if (i < XQ4)            { src = x;      hi = xh; lo = xl;      j = i; }
    else if (i < XQ4+WQ4)   { src = qkv_w;  hi = wh; lo = wl;      j = i - XQ4; }
    else                    { src = proj_w; hi = ph; lo = nullptr; j = i - XQ4 - WQ4; }
    float4 v = ((const float4*)src)[j];
    _Float16 h0 = (_Float16)v.x, h1 = (_Float16)v.y, h2_ = (_Float16)v.z, h3 = (_Float16)v.w;
    uint2 hv = make_uint2((u32)*(u16*)&h0 | ((u32)*(u16*)&h1 << 16),
                          (u32)*(u16*)&h2_ | ((u32)*(u16*)&h3 << 16));
    ((uint2*)hi)[j] = hv;
    if (lo) {
      _Float16 l0 = (_Float16)(v.x - (float)h0), l1 = (_Float16)(v.y - (float)h1);
      _Float16 l2 = (_Float16)(v.z - (float)h2_), l3 = (_Float16)(v.w - (float)h3);
      uint2 lv = make_uint2((u32)*(u16*)&l0 | ((u32)*(u16*)&l1 << 16),
                            (u32)*(u16*)&l2 | ((u32)*(u16*)&l3 << 16));
      ((uint2*)lo)[j] = lv;
    }
  }
}

// ---------------- MFMA GEMM, f16 split, C[r,o] = sum_c A[r,c]*W[o,c] ----------------
// 1D grid, XCD-chunked bijective remap, col-fastest within chunk.
// 2-phase loop (stage-next before compute, one vmcnt(0)+barrier per K-step) —
// the proven round-11 structure; counted-vmcnt graft measured null (round 12).
// MODE 0: qkv, A = xh/xl planes; q/k cols split-3, v cols hi*hi; q/k out as hi/lo planes.
// MODE 1: proj, A = aoh f16, hi-only + bias.
template<int MODE>
__global__ __launch_bounds__(256)
void gemm_mfma(const u16* __restrict__ Ah, const u16* __restrict__ Al,
               const u16* __restrict__ Wh, const u16* __restrict__ Wl,
               u16* __restrict__ qh_, u16* __restrict__ ql_,
               u16* __restrict__ kh_, u16* __restrict__ kl_, u16* __restrict__ vb_,
               const float* __restrict__ bias, float* __restrict__ dout)
{
  constexpr int NPL = (MODE == 1) ? 2 : 4;
  constexpr int NBX = (MODE == 1) ? 6 : 18;     // col blocks
  constexpr int NWG = NBX * 99;
  constexpr int Q8 = NWG / 8, R8 = NWG % 8;
  __shared__ u16 lds[2][NPL][4096];   // [buf][plane][128 rows x 32 f16]
  const int tid = threadIdx.x;
  const int lane = tid & 63, w = tid >> 6;
  const int wm = w >> 1, wn = w & 1;
  const int wg = blockIdx.x;
  const int xcd = wg & 7, cidx = wg >> 3;
  const int work = (xcd < R8 ? xcd*(Q8+1) : R8*(Q8+1) + (xcd-R8)*Q8) + cidx;
  const int row0 = (work / NBX) * 128, col0 = (work % NBX) * 128;
  const bool dolo = (MODE == 0) && (col0 < 1536);   // q/k need split-3; v hi-only

  f32x4 acc[4][4];
  #pragma unroll
  for (int mi = 0; mi < 4; ++mi)
    #pragma unroll
    for (int ni = 0; ni < 4; ++ni) acc[mi][ni] = (f32x4){0.f, 0.f, 0.f, 0.f};

  auto stage = [&](int buf, int kt) {
    const int c0 = kt * 32;
    #pragma unroll
    for (int j = 0; j < 2; ++j) {
      const int r0 = w*32 + j*16;
      const int lrow = r0 + (lane >> 2);
      const int slot = (lane & 3) ^ (lrow & 3);
      int ar = row0 + lrow; if (ar > BNROWS-1) ar = BNROWS-1;
      const size_t ga = (size_t)ar * 768 + c0 + slot*8;
      const size_t gb = (size_t)(col0 + lrow) * 768 + c0 + slot*8;
      GLOAD16(Ah + ga, &lds[buf][0][r0*32]);
      GLOAD16(Wh + gb, &lds[buf][1][r0*32]);
      if constexpr (MODE == 0) {
        if (dolo) {
          GLOAD16(Al + ga, &lds[buf][2][r0*32]);
          GLOAD16(Wl + gb, &lds[buf][3][r0*32]);
        }
      }
    }
  };

  auto compute = [&](int buf) {
    f16x8 ah[4], bh[4];
    const int g = lane >> 4;
    int offa[4], offb[4];
    #pragma unroll
    for (int mi = 0; mi < 4; ++mi) {
      int arow = wm*64 + mi*16 + (lane & 15);
      offa[mi] = arow*32 + ((g ^ (arow & 3)) << 3);
      ah[mi] = *(const f16x8*)&lds[buf][0][offa[mi]];
    }
    #pragma unroll
    for (int ni = 0; ni < 4; ++ni) {
      int brow = wn*64 + ni*16 + (lane & 15);
      offb[ni] = brow*32 + ((g ^ (brow & 3)) << 3);
      bh[ni] = *(const f16x8*)&lds[buf][1][offb[ni]];
    }
    #pragma unroll
    for (int mi = 0; mi < 4; ++mi)
      #pragma unroll
      for (int ni = 0; ni < 4; ++ni)
        acc[mi][ni] = __builtin_amdgcn_mfma_f32_16x16x32_f16(ah[mi], bh[ni], acc[mi][ni], 0, 0, 0);
    if constexpr (MODE == 0) {
      if (dolo) {
        f16x8 al[4], bl[4];
        #pragma unroll
        for (int mi = 0; mi < 4; ++mi) al[mi] = *(const f16x8*)&lds[buf][2][offa[mi]];
        #pragma unroll
        for (int ni = 0; ni < 4; ++ni) bl[ni] = *(const f16x8*)&lds[buf][3][offb[ni]];
        #pragma unroll
        for (int mi = 0; mi < 4; ++mi)
          #pragma unroll
          for (int ni = 0; ni < 4; ++ni) {
            acc[mi][ni] = __builtin_amdgcn_mfma_f32_16x16x32_f16(ah[mi], bl[ni], acc[mi][ni], 0, 0, 0);
            acc[mi][ni] = __builtin_amdgcn_mfma_f32_16x16x32_f16(al[mi], bh[ni], acc[mi][ni], 0, 0, 0);
          }
      }
    }
  };

  stage(0, 0);
  asm volatile("s_waitcnt vmcnt(0)" ::: "memory");
  __syncthreads();
  int cur = 0;
  for (int kt = 0; kt < 24; ++kt) {
    if (kt < 23) stage(cur ^ 1, kt + 1);
    compute(cur);
    asm volatile("s_waitcnt vmcnt(0)" ::: "memory");
    __syncthreads();
    cur ^= 1;
  }

  float* biasl = nullptr;
  if constexpr (MODE == 1) {
    biasl = (float*)&lds[0][0][0];
    if (tid < 128) biasl[tid] = bias[col0 + tid];
    __syncthreads();
  }
  #pragma unroll
  for (int mi = 0; mi < 4; ++mi) {
    #pragma unroll
    for (int t = 0; t < 4; ++t) {
      int r = row0 + wm*64 + mi*16 + (lane >> 4)*4 + t;
      if (r >= BNROWS) continue;
      if constexpr (MODE == 0) {
        int b_ = r / 197, n_ = r - b_*197;
        #pragma unroll
        for (int ni = 0; ni < 4; ++ni) {
          int o = col0 + wn*64 + ni*16 + (lane & 15);
          float val = acc[mi][ni][t];
          int tq = o / 768, rem = o - tq*768;
          int hh = rem >> 6, dd = rem & 63;
          size_t dst = ((size_t)(b_*12 + hh)*197 + n_)*64 + dd;
          u16 hi = f2h(val);
          if (tq == 0)      { qh_[dst] = hi; ql_[dst] = f2h(val - h2f(hi)); }
          else if (tq == 1) { kh_[dst] = hi; kl_[dst] = f2h(val - h2f(hi)); }
          else              vb_[dst] = hi;
        }
      } else {
        #pragma unroll
        for (int ni = 0; ni < 4; ++ni) {
          int o = col0 + wn*64 + ni*16 + (lane & 15);
          dout[(size_t)r*768 + o] = acc[mi][ni][t] + biasl[o - col0];
        }
      }
    }
  }
}

// ---------------- Quantize via MFMA distance GEMM + fp64 rescue for near-ties ----------
__global__ __launch_bounds__(256)
void quant_mfma(const float* __restrict__ x, const float* __restrict__ qkv_w,
                const u16* __restrict__ qh, const u16* __restrict__ ql,
                const u16* __restrict__ kh, const u16* __restrict__ kl,
                const float* __restrict__ qe, const float* __restrict__ ke,
                u16* __restrict__ cq, u16* __restrict__ ck, float* __restrict__ pq)
{
  __shared__ __align__(16) float El[KCB*66];    // codebook fp32 (pad 66)
  __shared__ __align__(16) u16 Ehi[64*64];      // codebook f16 hi (rows 50..63 zero)
  __shared__ __align__(16) u16 Elo[64*64];      // codebook f16 lo
  __shared__ double e2d[KCB];
  __shared__ int idxb[NM];
  __shared__ float wred[4];
  const int tid = threadIdx.x;
  const int bh = blockIdx.x;
  const int which = blockIdx.y;
  const int b_ = bh / 12, h_ = bh - b_*12;
  const u16* feath = which ? kh : qh;
  const u16* featl = which ? kl : ql;
  const float* emb  = which ? ke : qe;
  u16* dst = which ? ck : cq;
  const size_t base = (size_t)bh * (197*64);
  const int lane = tid & 63, w = tid >> 6;
  const int ln = lane & 15, g = lane >> 4;

  for (int idx = tid; idx < KCB*64; idx += 256) {
    int kk = idx >> 6, i = idx & 63;
    float v = emb[h_*(KCB*64) + idx];
    El[kk*66 + i] = v;
    _Float16 hv = (_Float16)v;
    Ehi[idx] = *(u16*)&hv;
    _Float16 lv = (_Float16)(v - (float)hv);
    Elo[idx] = *(u16*)&lv;
  }
  for (int idx = tid; idx < 14*64; idx += 256) {
    Ehi[KCB*64 + idx] = 0; Elo[KCB*64 + idx] = 0;
  }
  if (tid >= 64 && tid < 128) {
    int i = tid - 64;
    dst[base + i] = feath[base + i];      // cls passthrough
  }
  __syncthreads();
  if (tid < KCB) {
    double s = 0.0;
    for (int i = 0; i < 64; ++i) { double e = (double)El[tid*66 + i]; s += e*e; }
    e2d[tid] = s;
  }
  __syncthreads();

  f16x8 Eah[4][2], Eal[4][2];
  float e2l[4][4];
  #pragma unroll
  for (int t = 0; t < 4; ++t) {
    #pragma unroll
    for (int s = 0; s < 2; ++s) {
      int off = (t*16 + ln)*64 + s*32 + g*8;
      Eah[t][s] = *(const f16x8*)&Ehi[off];
      Eal[t][s] = *(const f16x8*)&Elo[off];
    }
    #pragma unroll
    for (int r = 0; r < 4; ++r) {
      int c = t*16 + g*4 + r;
      e2l[t][r] = (c < KCB) ? (float)e2d[c] : 1e30f;
    }
  }

  float msum = 0.f;
  for (int nt = w; nt < 13; nt += 4) {
    int tok = nt*16 + ln;
    int tokc = tok < NM ? tok : NM-1;
    const u16* fh = feath + base + (size_t)(tokc+1)*64;
    const u16* fl = featl + base + (size_t)(tokc+1)*64;
    f16x8 fqh[2], fql[2];
    float f2 = 0.f;
    #pragma unroll
    for (int s = 0; s < 2; ++s) {
      uint4 uh = *(const uint4*)(fh + s*32 + g*8);
      uint4 ul = *(const uint4*)(fl + s*32 + g*8);
      fqh[s] = *(f16x8*)&uh;
      fql[s] = *(f16x8*)&ul;
      #pragma unroll
      for (int i = 0; i < 8; ++i) {
        float q = (float)fqh[s][i] + (float)fql[s][i];
        f2 = fmaf(q, q, f2);
      }
    }
    f32x4 dacc[4];
    #pragma unroll
    for (int t = 0; t < 4; ++t) dacc[t] = (f32x4){0.f,0.f,0.f,0.f};
    #pragma unroll
    for (int t = 0; t < 4; ++t)
      #pragma unroll
      for (int s = 0; s < 2; ++s) {
        dacc[t] = __builtin_amdgcn_mfma_f32_16x16x32_f16(Eah[t][s], fqh[s], dacc[t], 0, 0, 0);
        dacc[t] = __builtin_amdgcn_mfma_f32_16x16x32_f16(Eah[t][s], fql[s], dacc[t], 0, 0, 0);
        dacc[t] = __builtin_amdgcn_mfma_f32_16x16x32_f16(Eal[t][s], fqh[s], dacc[t], 0, 0, 0);
      }
    float d1 = 1e38f, d2 = 1e38f; int idx = 0;
    #pragma unroll
    for (int t = 0; t < 4; ++t)
      #pragma unroll
      for (int r = 0; r < 4; ++r) {
        int c = t*16 + g*4 + r;
        float d = fmaf(-2.f, dacc[t][r], e2l[t][r]);
        if (d < d1) { d2 = d1; d1 = d; idx = c; }
        else if (d < d2) d2 = d;
      }
    #pragma unroll
    for (int off = 16; off <= 32; off <<= 1) {
      float od1 = __shfl_xor(d1, off), od2 = __shfl_xor(d2, off);
      int   oi  = __shfl_xor(idx, off);
      float of2 = __shfl_xor(f2, off);
      f2 += of2;
      if (od1 < d1 || (od1 == d1 && oi < idx)) {
        d2 = fminf(d1, od2); d1 = od1; idx = oi;
      } else {
        d2 = fminf(d2, od1);
      }
    }
    bool valid = tok < NM;
    bool exact = false;
    u64 flags = __ballot(g == 0 && valid && (d2 - d1) < 1e-3f);
    while (flags) {
      int src = __ffsll(flags) - 1;
      flags &= flags - 1;
      int mrow = 1 + nt*16 + src;
      const float* xrow = x + (size_t)(b_*197 + mrow)*768;
      const float* wrow = qkv_w + (size_t)(which*768 + h_*64 + lane)*768;
      double qd0 = 0.0, qd1 = 0.0, qd2 = 0.0, qd3 = 0.0;
      for (int c = 0; c < 768; c += 4) {
        qd0 = fma((double)xrow[c],   (double)wrow[c],   qd0);
        qd1 = fma((double)xrow[c+1], (double)wrow[c+1], qd1);
        qd2 = fma((double)xrow[c+2], (double)wrow[c+2], qd2);
        qd3 = fma((double)xrow[c+3], (double)wrow[c+3], qd3);
      }
      double qd = (qd0 + qd1) + (qd2 + qd3);
      double bb = 1e300; int bi = 0;
      for (int kk = 0; kk < KCB; ++kk) {
        double df = qd - (double)El[kk*66 + lane];
        double sq = df*df;
        #pragma unroll
        for (int off = 32; off > 0; off >>= 1) sq += __shfl_xor(sq, off);
        if (sq < bb) { bb = sq; bi = kk; }
      }
      if (ln == src) { idx = bi; d1 = (float)bb; exact = true; }
    }
    if (g == 0 && valid) {
      idxb[tok] = idx;
      msum += exact ? d1 : (d1 + f2);
    }
  }
  __syncthreads();

  for (int idx = tid; idx < NM*64; idx += 256) {
    int mm = idx >> 6, i = idx & 63;
    dst[base + (size_t)(mm+1)*64 + i] = f2h(El[idxb[mm]*66 + i]);
  }

  #pragma unroll
  for (int off = 8; off > 0; off >>= 1) msum += __shfl_down(msum, off);
  if (lane == 0) wred[w] = msum;
  __syncthreads();
  if (tid == 0) pq[which*768 + bh] = wred[0]+wred[1]+wred[2]+wred[3];
}

// ---------------- fused attention via MFMA, SINGLE-PASS online softmax ----------
__global__ __launch_bounds__(256)
void fused_attn_mfma(const u16* __restrict__ qh, const u16* __restrict__ kh,
                     const u16* __restrict__ cq, const u16* __restrict__ ck,
                     const u16* __restrict__ vb,
                     u16* __restrict__ aoh, float* __restrict__ pkl)
{
  __shared__ __align__(16) u16 Kf[200*64];    // XOR-swizzled rows (slot^=row&7)
  __shared__ __align__(16) u16 CKf[200*64];
  __shared__ __align__(16) u16 Vt[64*212];    // V transposed [d][m], stride 212
  __shared__ float wred[4];
  const int tid = threadIdx.x;
  const int bh = blockIdx.x;
  const int b_ = bh / 12, h_ = bh - b_*12;
  const size_t base = (size_t)bh * (197*64);
  const u32* kh32 = (const u32*)kh;
  const u32* ck32 = (const u32*)ck;
  const u32* vb32 = (const u32*)vb;
  const size_t base2 = base >> 1;

  for (int idx = tid; idx < 197*32; idx += 256) {
    int m = idx >> 5, j = idx & 31;
    int dsti = m*32 + (((j >> 2) ^ (m & 7)) << 2) + (j & 3);
    ((u32*)Kf)[dsti] = kh32[base2 + idx];
    ((u32*)CKf)[dsti] = ck32[base2 + idx];
    u32 v2 = vb32[base2 + idx];
    Vt[(2*j)*212 + m]   = (u16)(v2 & 0xffff);
    Vt[(2*j+1)*212 + m] = (u16)(v2 >> 16);
  }
  for (int idx = tid; idx < 96; idx += 256) {
    int m = 197 + (idx >> 5), j = idx & 31;
    int dsti = m*32 + (((j >> 2) ^ (m & 7)) << 2) + (j & 3);
    ((u32*)Kf)[dsti] = 0; ((u32*)CKf)[dsti] = 0;
  }
  for (int idx = tid; idx < 64*15; idx += 256) {
    int d = idx / 15, mc = 197 + idx % 15;
    Vt[d*212 + mc] = 0;
  }
  __syncthreads();

  const int lane = tid & 63, w = tid >> 6;
  const int ln = lane & 15, g = lane >> 4;
  float klacc = 0.f;

  for (int nt = w; nt < 13; nt += 4) {
    const int n0 = nt*16;
    const int nb = n0 + ln;
    f16x8 fq[2], fcq[2];
    #pragma unroll
    for (int s = 0; s < 2; ++s) {
      uint4 qu = *(const uint4*)(qh + base + (size_t)nb*64 + s*32 + g*8);
      fq[s] = *(f16x8*)&qu;
      uint4 cu = *(const uint4*)(cq + base + (size_t)nb*64 + s*32 + g*8);
      fcq[s] = *(f16x8*)&cu;
    }

    float Ma = -3e38f, Mq = -3e38f;
    float aS = 0.f, aT = 0.f, qS = 0.f, cross = 0.f;
    f32x4 ov[4];
    #pragma unroll
    for (int dt = 0; dt < 4; ++dt) ov[dt] = (f32x4){0.f,0.f,0.f,0.f};

    for (int t = 0; t < 13; ++t) {
      int mrow = t*16 + ln; if (mrow > 199) mrow = 199;
      const char* kb8 = (const char*)Kf + mrow*128;
      const char* cb8 = (const char*)CKf + mrow*128;
      int sw = (mrow & 7) << 4;
      f32x4 sa = (f32x4){0.f,0.f,0.f,0.f}, sq = (f32x4){0.f,0.f,0.f,0.f};
      sa = __builtin_amdgcn_mfma_f32_16x16x32_f16(*(const f16x8*)(kb8 + (( g     <<4) ^ sw)), fq[0], sa, 0,0,0);
      sa = __builtin_amdgcn_mfma_f32_16x16x32_f16(*(const f16x8*)(kb8 + (((4+g)<<4) ^ sw)), fq[1], sa, 0,0,0);
      sq = __builtin_amdgcn_mfma_f32_16x16x32_f16(*(const f16x8*)(cb8 + (( g     <<4) ^ sw)), fcq[0], sq, 0,0,0);
      sq = __builtin_amdgcn_mfma_f32_16x16x32_f16(*(const f16x8*)(cb8 + (((4+g)<<4) ^ sw)), fcq[1], sq, 0,0,0);
      int mbase = t*16 + g*4;
      float tma = -3e38f, tmq = -3e38f;
      #pragma unroll
      for (int r = 0; r < 4; ++r) {
        bool v = (mbase + r) < 197;
        tma = fmaxf(tma, v ? sa[r] : -3e38f);
        tmq = fmaxf(tmq, v ? sq[r] : -3e38f);
      }
      tma = fmaxf(tma, __shfl_xor(tma, 16)); tma = fmaxf(tma, __shfl_xor(tma, 32));
      tmq = fmaxf(tmq, __shfl_xor(tmq, 16)); tmq = fmaxf(tmq, __shfl_xor(tmq, 32));
      float Ma2 = fmaxf(Ma, tma), Mq2 = fmaxf(Mq, tmq);
      float sca = __expf(0.125f*(Ma - Ma2));
      float scq = __expf(0.125f*(Mq - Mq2));
      Ma = Ma2; Mq = Mq2;
      aS *= sca; aT *= sca; qS *= scq; cross *= sca*scq;
      float s0 = __shfl(scq, g*4+0), s1 = __shfl(scq, g*4+1);
      float s2 = __shfl(scq, g*4+2), s3 = __shfl(scq, g*4+3);
      #pragma unroll
      for (int dt = 0; dt < 4; ++dt) {
        ov[dt][0] *= s0; ov[dt][1] *= s1; ov[dt][2] *= s2; ov[dt][3] *= s3;
      }
      const float mla = 0.125f*Ma, mlq = 0.125f*Mq;
      float eqv[4];
      #pragma unroll
      for (int r = 0; r < 4; ++r) {
        bool v = (mbase + r) < 197;
        float ea = v ? __expf(fmaf(sa[r], 0.125f, -mla)) : 0.f;
        float eq = v ? __expf(fmaf(sq[r], 0.125f, -mlq)) : 0.f;
        aS += ea;
        aT = fmaf(ea, sa[r], aT);
        qS += eq;
        cross = fmaf(ea, eq, cross);
        eqv[r] = eq;
      }
      f16x4 qaf = {(_Float16)eqv[0], (_Float16)eqv[1], (_Float16)eqv[2], (_Float16)eqv[3]};
      #pragma unroll
      for (int dt = 0; dt < 4; ++dt) {
        f16x4 bv = *(const f16x4*)(Vt + (dt*16 + ln)*212 + t*16 + g*4);
        ov[dt] = __builtin_amdgcn_mfma_f32_16x16x16f16(qaf, bv, ov[dt], 0, 0, 0);
      }
    }
    aS += __shfl_xor(aS, 16); aS += __shfl_xor(aS, 32);
    aT += __shfl_xor(aT, 16); aT += __shfl_xor(aT, 32);
    qS += __shfl_xor(qS, 16); qS += __shfl_xor(qS, 32);
    cross += __shfl_xor(cross, 16); cross += __shfl_xor(cross, 32);

    if (g == 0 && nb < 197) {
      float rowkl = 0.125f*(aT/aS) - 0.125f*Ma - __logf(aS) - cross/(aS*qS);
      klacc += rowkl;
    }
    #pragma unroll
    for (int r = 0; r < 4; ++r) {
      int nl = g*4 + r;
      int nglob = n0 + nl;
      if (nglob >= 197) continue;
      float qSn = __shfl(qS, nl);
      float inv = __frcp_rn(qSn);
      size_t obase = ((size_t)(b_*197 + nglob))*768 + h_*64;
      #pragma unroll
      for (int dt = 0; dt < 4; ++dt)
        aoh[obase + dt*16 + ln] = f2h(ov[dt][r] * inv);
    }
  }

  #pragma unroll
  for (int off = 32; off > 0; off >>= 1) klacc += __shfl_down(klacc, off);
  if (lane == 0) wred[w] = klacc;
  __syncthreads();
  if (tid == 0) pkl[bh] = wred[0] + wred[1] + wred[2] + wred[3];
}

// ---------------- deterministic loss finalize ----------------
__global__ __launch_bounds__(256)
void finalize_kernel(const float* __restrict__ pq, const float* __restrict__ pkl,
                     float* __restrict__ dout)
{
  __shared__ double red[256];
  const int tid = threadIdx.x;
  double s0 = 0.0, s1 = 0.0;
  for (int i = tid; i < 1536; i += 256) s0 += (double)pq[i];
  for (int i = tid; i < 768; i += 256) s1 += (double)pkl[i];
  red[tid] = s0; __syncthreads();
  for (int off = 128; off > 0; off >>= 1) { if (tid < off) red[tid] += red[tid+off]; __syncthreads(); }
  double mse = red[0];
  __syncthreads();
  red[tid] = s1; __syncthreads();
  for (int off = 128; off > 0; off >>= 1) { if (tid < off) red[tid] += red[tid+off]; __syncthreads(); }
  double kl = red[0];
  if (tid == 0) dout[SZ] = (float)(mse / 9633792.0 + kl / 29805312.0);
}

extern "C" void kernel_launch(void* const* d_in, const int* in_sizes, int n_in,
                              void* d_out, int out_size, void* d_ws, size_t ws_size,
                              hipStream_t stream)
{
  const float* x      = (const float*)d_in[0];
  const float* qkv_w  = (const float*)d_in[1];
  const float* proj_w = (const float*)d_in[2];
  const float* proj_b = (const float*)d_in[3];
  const float* qe     = (const float*)d_in[4];
  const float* ke     = (const float*)d_in[5];
  float* out = (float*)d_out;

  u16* ws16 = (u16*)d_ws;
  u16* qh_ = ws16;                       // SZ f16 planes
  u16* ql_ = qh_ + SZ;
  u16* kh_ = ql_ + SZ;
  u16* kl_ = kh_ + SZ;
  u16* vb_ = kl_ + SZ;
  u16* cq_ = vb_ + SZ;
  u16* ck_ = cq_ + SZ;
  u16* aoh_= ck_ + SZ;
  u16* xh_ = aoh_ + SZ;
  u16* xl_ = xh_ + SZ;
  u16* wh_ = xl_ + SZ;                   // WQKV f16
  u16* wl_ = wh_ + WQKV;
  u16* ph_ = wl_ + WQKV;                 // WPRJ f16
  float* pq_ = (float*)(ph_ + WPRJ);     // 1536
  float* pkl_= pq_ + 1536;               // 768

  dim3 blk(256);
  split_all<<<dim3(2048), blk, 0, stream>>>(x, qkv_w, proj_w, xh_, xl_, wh_, wl_, ph_);
  gemm_mfma<0><<<dim3(99*18), blk, 0, stream>>>(xh_, xl_, wh_, wl_, qh_, ql_, kh_, kl_, vb_, nullptr, nullptr);
  quant_mfma<<<dim3(768, 2), blk, 0, stream>>>(x, qkv_w, qh_, ql_, kh_, kl_, qe, ke, cq_, ck_, pq_);
  fused_attn_mfma<<<dim3(768), blk, 0, stream>>>(qh_, kh_, cq_, ck_, vb_, aoh_, pkl_);
  gemm_mfma<1><<<dim3(99*6), blk, 0, stream>>>(aoh_, nullptr, ph_, nullptr, nullptr, nullptr, nullptr, nullptr, nullptr, proj_b, out);
  finalize_kernel<<<dim3(1), blk, 0, stream>>>(pq_, pkl_, out);
}

// Round 14
// 320.445 us; speedup vs baseline: 1.0711x; 1.0465x over previous
//
#include <hip/hip_runtime.h>
#include <math.h>

#define NB 64
#define NN 197
#define NC 768
#define NH 12
#define ND 64
#define KCB 50
#define NM (NN-1)                    // 196
#define BNROWS (NB*NN)               // 12608
#define SZ ((size_t)NB*NH*NN*ND)     // 9,682,944
#define WQKV ((size_t)2304*768)      // 1,769,472
#define WPRJ ((size_t)768*768)       // 589,824

typedef unsigned short u16;
typedef unsigned int u32;
typedef unsigned long long u64;
typedef _Float16 h2 __attribute__((ext_vector_type(2)));
typedef _Float16 f16x4 __attribute__((ext_vector_type(4)));
typedef _Float16 f16x8 __attribute__((ext_vector_type(8)));
typedef float f32x4 __attribute__((ext_vector_type(4)));

#define GLOAD16(gp, lp) __builtin_amdgcn_global_load_lds( \
    (const __attribute__((address_space(1))) void*)(gp),  \
    (__attribute__((address_space(3))) void*)(lp), 16, 0, 0)

__device__ __forceinline__ u16 f2h(float x) {
  _Float16 h = (_Float16)x;
  return *(u16*)&h;
}
__device__ __forceinline__ float h2f(u16 b) { _Float16 h = *(_Float16*)&b; return (float)h; }

// ---------------- fused split: x (hi+lo), qkv_w (hi+lo), proj_w (hi) in ONE launch ----------
#define XQ4 ((int)(SZ/4))      // 2,420,736 quads
#define WQ4 ((int)(WQKV/4))    //   442,368
#define PQ4 ((int)(WPRJ/4))    //   147,456
#define TOTQ4 (XQ4 + WQ4 + PQ4)

__global__ __launch_bounds__(256)
void split_all(const float* __restrict__ x, const float* __restrict__ qkv_w,
               const float* __restrict__ proj_w,
               u16* __restrict__ xh, u16* __restrict__ xl,
               u16* __restrict__ wh, u16* __restrict__ wl,
               u16* __restrict__ ph)
{
  for (int i = blockIdx.x*256 + threadIdx.x; i < TOTQ4; i += gridDim.x*256) {
    const float* src; u16* hi; u16* lo; int j;
    if (i < XQ4)            { src = x;      hi = xh; lo = xl;      j = i; }
    else if (i < XQ4+WQ4)   { src = qkv_w;  hi = wh; lo = wl;      j = i - XQ4; }
    else                    { src = proj_w; hi = ph; lo = nullptr; j = i - XQ4 - WQ4; }
    float4 v = ((const float4*)src)[j];
    _Float16 h0 = (_Float16)v.x, h1 = (_Float16)v.y, h2_ = (_Float16)v.z, h3 = (_Float16)v.w;
    uint2 hv = make_uint2((u32)*(u16*)&h0 | ((u32)*(u16*)&h1 << 16),
                          (u32)*(u16*)&h2_ | ((u32)*(u16*)&h3 << 16));
    ((uint2*)hi)[j] = hv;
    if (lo) {
      _Float16 l0 = (_Float16)(v.x - (float)h0), l1 = (_Float16)(v.y - (float)h1);
      _Float16 l2 = (_Float16)(v.z - (float)h2_), l3 = (_Float16)(v.w - (float)h3);
      uint2 lv = make_uint2((u32)*(u16*)&l0 | ((u32)*(u16*)&l1 << 16),
                            (u32)*(u16*)&l2 | ((u32)*(u16*)&l3 << 16));
      ((uint2*)lo)[j] = lv;
    }
  }
}

// ---------------- MFMA GEMM, f16 split, C[r,o] = sum_c A[r,c]*W[o,c] ----------------
// 1D grid, XCD-chunked bijective remap; SERPENTINE col order within chunk (odd rows
// reverse cols) so the W working set wraps smoothly in the 4MB L2 instead of thrashing.
// MODE 0: qkv, A = xh/xl planes; q/k cols split-3, v cols hi*hi; q/k out as hi/lo planes.
//         Coalesced epilogue: stage wave tile in LDS, drain uint4 rows (fixes 2x write amp).
// MODE 1: proj, A = aoh f16, hi-only + bias.
template<int MODE>
__global__ __launch_bounds__(256)
void gemm_mfma(const u16* __restrict__ Ah, const u16* __restrict__ Al,
               const u16* __restrict__ Wh, const u16* __restrict__ Wl,
               u16* __restrict__ qh_, u16* __restrict__ ql_,
               u16* __restrict__ kh_, u16* __restrict__ kl_, u16* __restrict__ vb_,
               const float* __restrict__ bias, float* __restrict__ dout)
{
  constexpr int NPL = (MODE == 1) ? 2 : 4;
  constexpr int NBX = (MODE == 1) ? 6 : 18;     // col blocks
  constexpr int NWG = NBX * 99;
  constexpr int Q8 = NWG / 8, R8 = NWG % 8;
  __shared__ u16 lds[2][NPL][4096];   // [buf][plane][128 rows x 32 f16]
  const int tid = threadIdx.x;
  const int lane = tid & 63, w = tid >> 6;
  const int wm = w >> 1, wn = w & 1;
  const int wg = blockIdx.x;
  const int xcd = wg & 7, cidx = wg >> 3;
  const int work = (xcd < R8 ? xcd*(Q8+1) : R8*(Q8+1) + (xcd-R8)*Q8) + cidx;
  const int wrow = work / NBX;
  const int wc = work - wrow*NBX;
  const int coli = (wrow & 1) ? (NBX-1-wc) : wc;   // serpentine
  const int row0 = wrow * 128, col0 = coli * 128;
  const bool dolo = (MODE == 0) && (col0 < 1536);   // q/k need split-3; v hi-only

  f32x4 acc[4][4];
  #pragma unroll
  for (int mi = 0; mi < 4; ++mi)
    #pragma unroll
    for (int ni = 0; ni < 4; ++ni) acc[mi][ni] = (f32x4){0.f, 0.f, 0.f, 0.f};

  auto stage = [&](int buf, int kt) {
    const int c0 = kt * 32;
    #pragma unroll
    for (int j = 0; j < 2; ++j) {
      const int r0 = w*32 + j*16;
      const int lrow = r0 + (lane >> 2);
      const int slot = (lane & 3) ^ (lrow & 3);
      int ar = row0 + lrow; if (ar > BNROWS-1) ar = BNROWS-1;
      const size_t ga = (size_t)ar * 768 + c0 + slot*8;
      const size_t gb = (size_t)(col0 + lrow) * 768 + c0 + slot*8;
      GLOAD16(Ah + ga, &lds[buf][0][r0*32]);
      GLOAD16(Wh + gb, &lds[buf][1][r0*32]);
      if constexpr (MODE == 0) {
        if (dolo) {
          GLOAD16(Al + ga, &lds[buf][2][r0*32]);
          GLOAD16(Wl + gb, &lds[buf][3][r0*32]);
        }
      }
    }
  };

  auto compute = [&](int buf) {
    f16x8 ah[4], bh[4];
    const int g = lane >> 4;
    int offa[4], offb[4];
    #pragma unroll
    for (int mi = 0; mi < 4; ++mi) {
      int arow = wm*64 + mi*16 + (lane & 15);
      offa[mi] = arow*32 + ((g ^ (arow & 3)) << 3);
      ah[mi] = *(const f16x8*)&lds[buf][0][offa[mi]];
    }
    #pragma unroll
    for (int ni = 0; ni < 4; ++ni) {
      int brow = wn*64 + ni*16 + (lane & 15);
      offb[ni] = brow*32 + ((g ^ (brow & 3)) << 3);
      bh[ni] = *(const f16x8*)&lds[buf][1][offb[ni]];
    }
    #pragma unroll
    for (int mi = 0; mi < 4; ++mi)
      #pragma unroll
      for (int ni = 0; ni < 4; ++ni)
        acc[mi][ni] = __builtin_amdgcn_mfma_f32_16x16x32_f16(ah[mi], bh[ni], acc[mi][ni], 0, 0, 0);
    if constexpr (MODE == 0) {
      if (dolo) {
        f16x8 al[4], bl[4];
        #pragma unroll
        for (int mi = 0; mi < 4; ++mi) al[mi] = *(const f16x8*)&lds[buf][2][offa[mi]];
        #pragma unroll
        for (int ni = 0; ni < 4; ++ni) bl[ni] = *(const f16x8*)&lds[buf][3][offb[ni]];
        #pragma unroll
        for (int mi = 0; mi < 4; ++mi)
          #pragma unroll
          for (int ni = 0; ni < 4; ++ni) {
            acc[mi][ni] = __builtin_amdgcn_mfma_f32_16x16x32_f16(ah[mi], bl[ni], acc[mi][ni], 0, 0, 0);
            acc[mi][ni] = __builtin_amdgcn_mfma_f32_16x16x32_f16(al[mi], bh[ni], acc[mi][ni], 0, 0, 0);
          }
      }
    }
  };

  stage(0, 0);
  asm volatile("s_waitcnt vmcnt(0)" ::: "memory");
  __syncthreads();
  int cur = 0;
  for (int kt = 0; kt < 24; ++kt) {
    if (kt < 23) stage(cur ^ 1, kt + 1);
    compute(cur);
    asm volatile("s_waitcnt vmcnt(0)" ::: "memory");
    __syncthreads();
    cur ^= 1;
  }

  if constexpr (MODE == 0) {
    // coalesced epilogue: per-wave [16][72] hi + [16][72] lo staging in LDS (stride 72
    // keeps uint4 reads 16B-aligned), drain as contiguous uint4 row segments.
    u16* sc = ((u16*)lds) + w*2304;
    const int ch = col0 + wn*64;
    const int tq = ch / 768;
    const int hh = (ch - tq*768) >> 6;
    u16* dsth = (tq == 0) ? qh_ : (tq == 1 ? kh_ : vb_);
    u16* dstl = (tq == 0) ? ql_ : kl_;
    #pragma unroll
    for (int mi = 0; mi < 4; ++mi) {
      #pragma unroll
      for (int ni = 0; ni < 4; ++ni) {
        #pragma unroll
        for (int t = 0; t < 4; ++t) {
          int rl = (lane >> 4)*4 + t;
          int cl = ni*16 + (lane & 15);
          float val = acc[mi][ni][t];
          u16 hi = f2h(val);
          sc[rl*72 + cl] = hi;
          if (tq < 2) sc[1152 + rl*72 + cl] = f2h(val - h2f(hi));
        }
      }
      asm volatile("s_waitcnt lgkmcnt(0)" ::: "memory");
      __builtin_amdgcn_sched_barrier(0);
      #pragma unroll
      for (int pass = 0; pass < 2; ++pass) {
        int slot = pass*64 + lane;
        int rl = slot >> 3, seg = slot & 7;
        int r = row0 + wm*64 + mi*16 + rl;
        if (r < BNROWS) {
          int b_ = r / 197, n_ = r - b_*197;
          size_t dst = ((size_t)(b_*12 + hh)*197 + n_)*64 + seg*8;
          uint4 hv = *(const uint4*)&sc[rl*72 + seg*8];
          *(uint4*)(dsth + dst) = hv;
          if (tq < 2) {
            uint4 lv = *(const uint4*)&sc[1152 + rl*72 + seg*8];
            *(uint4*)(dstl + dst) = lv;
          }
        }
      }
      asm volatile("s_waitcnt lgkmcnt(0)" ::: "memory");
      __builtin_amdgcn_sched_barrier(0);
    }
  } else {
    float* biasl = (float*)&lds[0][0][0];
    if (tid < 128) biasl[tid] = bias[col0 + tid];
    __syncthreads();
    #pragma unroll
    for (int mi = 0; mi < 4; ++mi) {
      #pragma unroll
      for (int t = 0; t < 4; ++t) {
        int r = row0 + wm*64 + mi*16 + (lane >> 4)*4 + t;
        if (r >= BNROWS) continue;
        #pragma unroll
        for (int ni = 0; ni < 4; ++ni) {
          int o = col0 + wn*64 + ni*16 + (lane & 15);
          dout[(size_t)r*768 + o] = acc[mi][ni][t] + biasl[o - col0];
        }
      }
    }
  }
}

// ---------------- Quantize via MFMA distance GEMM + fp64 rescue for near-ties ----------
__global__ __launch_bounds__(256)
void quant_mfma(const float* __restrict__ x, const float* __restrict__ qkv_w,
                const u16* __restrict__ qh, const u16* __restrict__ ql,
                const u16* __restrict__ kh, const u16* __restrict__ kl,
                const float* __restrict__ qe, const float* __restrict__ ke,
                u16* __restrict__ cq, u16* __restrict__ ck, float* __restrict__ pq)
{
  __shared__ __align__(16) float El[KCB*66];    // codebook fp32 (pad 66)
  __shared__ __align__(16) u16 Ehi[64*64];      // codebook f16 hi (rows 50..63 zero)
  __shared__ __align__(16) u16 Elo[64*64];      // codebook f16 lo
  __shared__ double e2d[KCB];
  __shared__ int idxb[NM];
  __shared__ float wred[4];
  const int tid = threadIdx.x;
  const int bh = blockIdx.x;
  const int which = blockIdx.y;
  const int b_ = bh / 12, h_ = bh - b_*12;
  const u16* feath = which ? kh : qh;
  const u16* featl = which ? kl : ql;
  const float* emb  = which ? ke : qe;
  u16* dst = which ? ck : cq;
  const size_t base = (size_t)bh * (197*64);
  const int lane = tid & 63, w = tid >> 6;
  const int ln = lane & 15, g = lane >> 4;

  for (int idx = tid; idx < KCB*64; idx += 256) {
    int kk = idx >> 6, i = idx & 63;
    float v = emb[h_*(KCB*64) + idx];
    El[kk*66 + i] = v;
    _Float16 hv = (_Float16)v;
    Ehi[idx] = *(u16*)&hv;
    _Float16 lv = (_Float16)(v - (float)hv);
    Elo[idx] = *(u16*)&lv;
  }
  for (int idx = tid; idx < 14*64; idx += 256) {
    Ehi[KCB*64 + idx] = 0; Elo[KCB*64 + idx] = 0;
  }
  if (tid >= 64 && tid < 128) {
    int i = tid - 64;
    dst[base + i] = feath[base + i];      // cls passthrough
  }
  __syncthreads();
  if (tid < KCB) {
    double s = 0.0;
    for (int i = 0; i < 64; ++i) { double e = (double)El[tid*66 + i]; s += e*e; }
    e2d[tid] = s;
  }
  __syncthreads();

  f16x8 Eah[4][2], Eal[4][2];
  float e2l[4][4];
  #pragma unroll
  for (int t = 0; t < 4; ++t) {
    #pragma unroll
    for (int s = 0; s < 2; ++s) {
      int off = (t*16 + ln)*64 + s*32 + g*8;
      Eah[t][s] = *(const f16x8*)&Ehi[off];
      Eal[t][s] = *(const f16x8*)&Elo[off];
    }
    #pragma unroll
    for (int r = 0; r < 4; ++r) {
      int c = t*16 + g*4 + r;
      e2l[t][r] = (c < KCB) ? (float)e2d[c] : 1e30f;
    }
  }

  float msum = 0.f;
  for (int nt = w; nt < 13; nt += 4) {
    int tok = nt*16 + ln;
    int tokc = tok < NM ? tok : NM-1;
    const u16* fh = feath + base + (size_t)(tokc+1)*64;
    const u16* fl = featl + base + (size_t)(tokc+1)*64;
    f16x8 fqh[2], fql[2];
    float f2 = 0.f;
    #pragma unroll
    for (int s = 0; s < 2; ++s) {
      uint4 uh = *(const uint4*)(fh + s*32 + g*8);
      uint4 ul = *(const uint4*)(fl + s*32 + g*8);
      fqh[s] = *(f16x8*)&uh;
      fql[s] = *(f16x8*)&ul;
      #pragma unroll
      for (int i = 0; i < 8; ++i) {
        float q = (float)fqh[s][i] + (float)fql[s][i];
        f2 = fmaf(q, q, f2);
      }
    }
    f32x4 dacc[4];
    #pragma unroll
    for (int t = 0; t < 4; ++t) dacc[t] = (f32x4){0.f,0.f,0.f,0.f};
    #pragma unroll
    for (int t = 0; t < 4; ++t)
      #pragma unroll
      for (int s = 0; s < 2; ++s) {
        dacc[t] = __builtin_amdgcn_mfma_f32_16x16x32_f16(Eah[t][s], fqh[s], dacc[t], 0, 0, 0);
        dacc[t] = __builtin_amdgcn_mfma_f32_16x16x32_f16(Eah[t][s], fql[s], dacc[t], 0, 0, 0);
        dacc[t] = __builtin_amdgcn_mfma_f32_16x16x32_f16(Eal[t][s], fqh[s], dacc[t], 0, 0, 0);
      }
    float d1 = 1e38f, d2 = 1e38f; int idx = 0;
    #pragma unroll
    for (int t = 0; t < 4; ++t)
      #pragma unroll
      for (int r = 0; r < 4; ++r) {
        int c = t*16 + g*4 + r;
        float d = fmaf(-2.f, dacc[t][r], e2l[t][r]);
        if (d < d1) { d2 = d1; d1 = d; idx = c; }
        else if (d < d2) d2 = d;
      }
    #pragma unroll
    for (int off = 16; off <= 32; off <<= 1) {
      float od1 = __shfl_xor(d1, off), od2 = __shfl_xor(d2, off);
      int   oi  = __shfl_xor(idx, off);
      float of2 = __shfl_xor(f2, off);
      f2 += of2;
      if (od1 < d1 || (od1 == d1 && oi < idx)) {
        d2 = fminf(d1, od2); d1 = od1; idx = oi;
      } else {
        d2 = fminf(d2, od1);
      }
    }
    bool valid = tok < NM;
    bool exact = false;
    u64 flags = __ballot(g == 0 && valid && (d2 - d1) < 1e-3f);
    while (flags) {
      int src = __ffsll(flags) - 1;
      flags &= flags - 1;
      int mrow = 1 + nt*16 + src;
      const float* xrow = x + (size_t)(b_*197 + mrow)*768;
      const float* wrow = qkv_w + (size_t)(which*768 + h_*64 + lane)*768;
      double qd0 = 0.0, qd1 = 0.0, qd2 = 0.0, qd3 = 0.0;
      for (int c = 0; c < 768; c += 4) {
        qd0 = fma((double)xrow[c],   (double)wrow[c],   qd0);
        qd1 = fma((double)xrow[c+1], (double)wrow[c+1], qd1);
        qd2 = fma((double)xrow[c+2], (double)wrow[c+2], qd2);
        qd3 = fma((double)xrow[c+3], (double)wrow[c+3], qd3);
      }
      double qd = (qd0 + qd1) + (qd2 + qd3);
      double bb = 1e300; int bi = 0;
      for (int kk = 0; kk < KCB; ++kk) {
        double df = qd - (double)El[kk*66 + lane];
        double sq = df*df;
        #pragma unroll
        for (int off = 32; off > 0; off >>= 1) sq += __shfl_xor(sq, off);
        if (sq < bb) { bb = sq; bi = kk; }
      }
      if (ln == src) { idx = bi; d1 = (float)bb; exact = true; }
    }
    if (g == 0 && valid) {
      idxb[tok] = idx;
      msum += exact ? d1 : (d1 + f2);
    }
  }
  __syncthreads();

  for (int idx = tid; idx < NM*64; idx += 256) {
    int mm = idx >> 6, i = idx & 63;
    dst[base + (size_t)(mm+1)*64 + i] = f2h(El[idxb[mm]*66 + i]);
  }

  #pragma unroll
  for (int off = 8; off > 0; off >>= 1) msum += __shfl_down(msum, off);
  if (lane == 0) wred[w] = msum;
  __syncthreads();
  if (tid == 0) pq[which*768 + bh] = wred[0]+wred[1]+wred[2]+wred[3];
}

// ---------------- fused attention via MFMA, SINGLE-PASS online softmax ----------
__global__ __launch_bounds__(256)
void fused_attn_mfma(const u16* __restrict__ qh, const u16* __restrict__ kh,
                     const u16* __restrict__ cq, const u16* __restrict__ ck,
                     const u16* __restrict__ vb,
                     u16* __restrict__ aoh, float* __restrict__ pkl)
{
  __shared__ __align__(16) u16 Kf[200*64];    // XOR-swizzled rows (slot^=row&7)
  __shared__ __align__(16) u16 CKf[200*64];
  __shared__ __align__(16) u16 Vt[64*212];    // V transposed [d][m], stride 212
  __shared__ float wred[4];
  const int tid = threadIdx.x;
  const int bh = blockIdx.x;
  const int b_ = bh / 12, h_ = bh - b_*12;
  const size_t base = (size_t)bh * (197*64);
  const u32* kh32 = (const u32*)kh;
  const u32* ck32 = (const u32*)ck;
  const u32* vb32 = (const u32*)vb;
  const size_t base2 = base >> 1;

  for (int idx = tid; idx < 197*32; idx += 256) {
    int m = idx >> 5, j = idx & 31;
    int dsti = m*32 + (((j >> 2) ^ (m & 7)) << 2) + (j & 3);
    ((u32*)Kf)[dsti] = kh32[base2 + idx];
    ((u32*)CKf)[dsti] = ck32[base2 + idx];
    u32 v2 = vb32[base2 + idx];
    Vt[(2*j)*212 + m]   = (u16)(v2 & 0xffff);
    Vt[(2*j+1)*212 + m] = (u16)(v2 >> 16);
  }
  for (int idx = tid; idx < 96; idx += 256) {
    int m = 197 + (idx >> 5), j = idx & 31;
    int dsti = m*32 + (((j >> 2) ^ (m & 7)) << 2) + (j & 3);
    ((u32*)Kf)[dsti] = 0; ((u32*)CKf)[dsti] = 0;
  }
  for (int idx = tid; idx < 64*15; idx += 256) {
    int d = idx / 15, mc = 197 + idx % 15;
    Vt[d*212 + mc] = 0;
  }
  __syncthreads();

  const int lane = tid & 63, w = tid >> 6;
  const int ln = lane & 15, g = lane >> 4;
  float klacc = 0.f;

  for (int nt = w; nt < 13; nt += 4) {
    const int n0 = nt*16;
    const int nb = n0 + ln;
    f16x8 fq[2], fcq[2];
    #pragma unroll
    for (int s = 0; s < 2; ++s) {
      uint4 qu = *(const uint4*)(qh + base + (size_t)nb*64 + s*32 + g*8);
      fq[s] = *(f16x8*)&qu;
      uint4 cu = *(const uint4*)(cq + base + (size_t)nb*64 + s*32 + g*8);
      fcq[s] = *(f16x8*)&cu;
    }

    float Ma = -3e38f, Mq = -3e38f;
    float aS = 0.f, aT = 0.f, qS = 0.f, cross = 0.f;
    f32x4 ov[4];
    #pragma unroll
    for (int dt = 0; dt < 4; ++dt) ov[dt] = (f32x4){0.f,0.f,0.f,0.f};

    for (int t = 0; t < 13; ++t) {
      int mrow = t*16 + ln; if (mrow > 199) mrow = 199;
      const char* kb8 = (const char*)Kf + mrow*128;
      const char* cb8 = (const char*)CKf + mrow*128;
      int sw = (mrow & 7) << 4;
      f32x4 sa = (f32x4){0.f,0.f,0.f,0.f}, sq = (f32x4){0.f,0.f,0.f,0.f};
      sa = __builtin_amdgcn_mfma_f32_16x16x32_f16(*(const f16x8*)(kb8 + (( g     <<4) ^ sw)), fq[0], sa, 0,0,0);
      sa = __builtin_amdgcn_mfma_f32_16x16x32_f16(*(const f16x8*)(kb8 + (((4+g)<<4) ^ sw)), fq[1], sa, 0,0,0);
      sq = __builtin_amdgcn_mfma_f32_16x16x32_f16(*(const f16x8*)(cb8 + (( g     <<4) ^ sw)), fcq[0], sq, 0,0,0);
      sq = __builtin_amdgcn_mfma_f32_16x16x32_f16(*(const f16x8*)(cb8 + (((4+g)<<4) ^ sw)), fcq[1], sq, 0,0,0);
      int mbase = t*16 + g*4;
      float tma = -3e38f, tmq = -3e38f;
      #pragma unroll
      for (int r = 0; r < 4; ++r) {
        bool v = (mbase + r) < 197;
        tma = fmaxf(tma, v ? sa[r] : -3e38f);
        tmq = fmaxf(tmq, v ? sq[r] : -3e38f);
      }
      tma = fmaxf(tma, __shfl_xor(tma, 16)); tma = fmaxf(tma, __shfl_xor(tma, 32));
      tmq = fmaxf(tmq, __shfl_xor(tmq, 16)); tmq = fmaxf(tmq, __shfl_xor(tmq, 32));
      float Ma2 = fmaxf(Ma, tma), Mq2 = fmaxf(Mq, tmq);
      float sca = __expf(0.125f*(Ma - Ma2));
      float scq = __expf(0.125f*(Mq - Mq2));
      Ma = Ma2; Mq = Mq2;
      aS *= sca; aT *= sca; qS *= scq; cross *= sca*scq;
      float s0 = __shfl(scq, g*4+0), s1 = __shfl(scq, g*4+1);
      float s2 = __shfl(scq, g*4+2), s3 = __shfl(scq, g*4+3);
      #pragma unroll
      for (int dt = 0; dt < 4; ++dt) {
        ov[dt][0] *= s0; ov[dt][1] *= s1; ov[dt][2] *= s2; ov[dt][3] *= s3;
      }
      const float mla = 0.125f*Ma, mlq = 0.125f*Mq;
      float eqv[4];
      #pragma unroll
      for (int r = 0; r < 4; ++r) {
        bool v = (mbase + r) < 197;
        float ea = v ? __expf(fmaf(sa[r], 0.125f, -mla)) : 0.f;
        float eq = v ? __expf(fmaf(sq[r], 0.125f, -mlq)) : 0.f;
        aS += ea;
        aT = fmaf(ea, sa[r], aT);
        qS += eq;
        cross = fmaf(ea, eq, cross);
        eqv[r] = eq;
      }
      f16x4 qaf = {(_Float16)eqv[0], (_Float16)eqv[1], (_Float16)eqv[2], (_Float16)eqv[3]};
      #pragma unroll
      for (int dt = 0; dt < 4; ++dt) {
        f16x4 bv = *(const f16x4*)(Vt + (dt*16 + ln)*212 + t*16 + g*4);
        ov[dt] = __builtin_amdgcn_mfma_f32_16x16x16f16(qaf, bv, ov[dt], 0, 0, 0);
      }
    }
    aS += __shfl_xor(aS, 16); aS += __shfl_xor(aS, 32);
    aT += __shfl_xor(aT, 16); aT += __shfl_xor(aT, 32);
    qS += __shfl_xor(qS, 16); qS += __shfl_xor(qS, 32);
    cross += __shfl_xor(cross, 16); cross += __shfl_xor(cross, 32);

    if (g == 0 && nb < 197) {
      float rowkl = 0.125f*(aT/aS) - 0.125f*Ma - __logf(aS) - cross/(aS*qS);
      klacc += rowkl;
    }
    #pragma unroll
    for (int r = 0; r < 4; ++r) {
      int nl = g*4 + r;
      int nglob = n0 + nl;
      if (nglob >= 197) continue;
      float qSn = __shfl(qS, nl);
      float inv = __frcp_rn(qSn);
      size_t obase = ((size_t)(b_*197 + nglob))*768 + h_*64;
      #pragma unroll
      for (int dt = 0; dt < 4; ++dt)
        aoh[obase + dt*16 + ln] = f2h(ov[dt][r] * inv);
    }
  }

  #pragma unroll
  for (int off = 32; off > 0; off >>= 1) klacc += __shfl_down(klacc, off);
  if (lane == 0) wred[w] = klacc;
  __syncthreads();
  if (tid == 0) pkl[bh] = wred[0] + wred[1] + wred[2] + wred[3];
}

// ---------------- deterministic loss finalize ----------------
__global__ __launch_bounds__(256)
void finalize_kernel(const float* __restrict__ pq, const float* __restrict__ pkl,
                     float* __restrict__ dout)
{
  __shared__ double red[256];
  const int tid = threadIdx.x;
  double s0 = 0.0, s1 = 0.0;
  for (int i = tid; i < 1536; i += 256) s0 += (double)pq[i];
  for (int i = tid; i < 768; i += 256) s1 += (double)pkl[i];
  red[tid] = s0; __syncthreads();
  for (int off = 128; off > 0; off >>= 1) { if (tid < off) red[tid] += red[tid+off]; __syncthreads(); }
  double mse = red[0];
  __syncthreads();
  red[tid] = s1; __syncthreads();
  for (int off = 128; off > 0; off >>= 1) { if (tid < off) red[tid] += red[tid+off]; __syncthreads(); }
  double kl = red[0];
  if (tid == 0) dout[SZ] = (float)(mse / 9633792.0 + kl / 29805312.0);
}

extern "C" void kernel_launch(void* const* d_in, const int* in_sizes, int n_in,
                              void* d_out, int out_size, void* d_ws, size_t ws_size,
                              hipStream_t stream)
{
  const float* x      = (const float*)d_in[0];
  const float* qkv_w  = (const float*)d_in[1];
  const float* proj_w = (const float*)d_in[2];
  const float* proj_b = (const float*)d_in[3];
  const float* qe     = (const float*)d_in[4];
  const float* ke     = (const float*)d_in[5];
  float* out = (float*)d_out;

  u16* ws16 = (u16*)d_ws;
  u16* qh_ = ws16;                       // SZ f16 planes
  u16* ql_ = qh_ + SZ;
  u16* kh_ = ql_ + SZ;
  u16* kl_ = kh_ + SZ;
  u16* vb_ = kl_ + SZ;
  u16* cq_ = vb_ + SZ;
  u16* ck_ = cq_ + SZ;
  u16* aoh_= ck_ + SZ;
  u16* xh_ = aoh_ + SZ;
  u16* xl_ = xh_ + SZ;
  u16* wh_ = xl_ + SZ;                   // WQKV f16
  u16* wl_ = wh_ + WQKV;
  u16* ph_ = wl_ + WQKV;                 // WPRJ f16
  float* pq_ = (float*)(ph_ + WPRJ);     // 1536
  float* pkl_= pq_ + 1536;               // 768

  dim3 blk(256);
  split_all<<<dim3(2048), blk, 0, stream>>>(x, qkv_w, proj_w, xh_, xl_, wh_, wl_, ph_);
  gemm_mfma<0><<<dim3(99*18), blk, 0, stream>>>(xh_, xl_, wh_, wl_, qh_, ql_, kh_, kl_, vb_, nullptr, nullptr);
  quant_mfma<<<dim3(768, 2), blk, 0, stream>>>(x, qkv_w, qh_, ql_, kh_, kl_, qe, ke, cq_, ck_, pq_);
  fused_attn_mfma<<<dim3(768), blk, 0, stream>>>(qh_, kh_, cq_, ck_, vb_, aoh_, pkl_);
  gemm_mfma<1><<<dim3(99*6), blk, 0, stream>>>(aoh_, nullptr, ph_, nullptr, nullptr, nullptr, nullptr, nullptr, nullptr, proj_b, out);
  finalize_kernel<<<dim3(1), blk, 0, stream>>>(pq_, pkl_, out);
}